// Round 1
// baseline (2740.882 us; speedup 1.0000x reference)
//
#include <hip/hip_runtime.h>
#include <hip/hip_bf16.h>

#define OUT_STRIDE 384
#define EPSV 1e-9f

typedef __attribute__((ext_vector_type(8))) short bf16x8;
typedef __attribute__((ext_vector_type(4))) float f32x4;

static __device__ __forceinline__ short f2bf(float f) {
    __hip_bfloat16 h = __float2bfloat16(f);
    return *reinterpret_cast<short*>(&h);
}

// Push-based scatter-add: one wave per edge, lane l handles dims 2l, 2l+1.
// out[dst, ocol0 + k] += X[src, xcol0 + k] * w  (optionally * Dn[src])
__global__ __launch_bounds__(256)
void scatter_kernel(const float* X, long xstride, long xcol0,
                    const int* __restrict__ src, const int* __restrict__ dst,
                    const float* __restrict__ w, const float* __restrict__ Dn,
                    int useDn, float* out, long ocol0, int nE)
{
    const int lane = threadIdx.x & 63;
    const int wave = (int)((blockIdx.x * blockDim.x + threadIdx.x) >> 6);
    const int nWaves = (int)((gridDim.x * blockDim.x) >> 6);
    for (int e = wave; e < nE; e += nWaves) {
        const int s = src[e];
        const int d = dst[e];
        float ww = w[e];
        if (useDn) ww *= Dn[s];
        const float2 v = *(const float2*)(X + (long)s * xstride + xcol0 + 2 * lane);
        float* o = out + (long)d * OUT_STRIDE + ocol0 + 2 * lane;
        atomicAdd(o, v.x * ww);
        atomicAdd(o + 1, v.y * ww);
    }
}

// Fused GEMM (bf16 MFMA) + bias + ReLU + LayerNorm(scale,offset) for all 3 hops.
// blockIdx.y = hop. Block handles 64 nodes; wave wv handles 16 nodes.
// hop 0: x = features[n];  hop i>0: x = out[n, i*128 : i*128+128] * Dn[n] (in-place region)
__global__ __launch_bounds__(256)
void transform_kernel(const float* __restrict__ features,
                      const float* __restrict__ Dn,
                      const float* __restrict__ Wf,
                      const float* __restrict__ bf,
                      const float* __restrict__ scf,
                      const float* __restrict__ off,
                      float* out, int N)
{
    const int hop = blockIdx.y;
    const int tid = threadIdx.x;
    const int lane = tid & 63;
    const int wv = tid >> 6;

    constexpr int XS = 136;  // padded row stride (bf16 elems): 272B -> spreads b128 reads to LDS BW floor
    __shared__ __attribute__((aligned(16))) short Wl[128 * XS];
    __shared__ __attribute__((aligned(16))) short Xl[64 * XS];

    // Stage W[hop] (128x128 f32 -> bf16)
    const float4* W4 = (const float4*)(Wf + (long)hop * 128 * 128);
    for (int idx = tid; idx < 128 * 32; idx += 256) {
        float4 v = W4[idx];
        int row = idx >> 5;
        int col = (idx & 31) * 4;
        short* p = &Wl[row * XS + col];
        p[0] = f2bf(v.x); p[1] = f2bf(v.y); p[2] = f2bf(v.z); p[3] = f2bf(v.w);
    }
    // Stage X tile (64 nodes x 128), with D_norm folding for hops 1,2
    const int n0 = blockIdx.x * 64;
    for (int idx = tid; idx < 64 * 32; idx += 256) {
        int r = idx >> 5;
        int col = (idx & 31) * 4;
        int n = n0 + r;
        float4 v = make_float4(0.f, 0.f, 0.f, 0.f);
        float m = 1.0f;
        if (n < N) {
            if (hop == 0) v = *(const float4*)(features + (long)n * 128 + col);
            else { v = *(const float4*)(out + (long)n * OUT_STRIDE + hop * 128 + col); m = Dn[n]; }
        }
        short* p = &Xl[r * XS + col];
        p[0] = f2bf(v.x * m); p[1] = f2bf(v.y * m); p[2] = f2bf(v.z * m); p[3] = f2bf(v.w * m);
    }
    __syncthreads();

    // MFMA: each wave -> 16 nodes x 128 cols. A: row=lane&15, k=(lane>>4)*8+j. B: col=lane&15 (W row), same k.
    f32x4 acc[8];
    #pragma unroll
    for (int c = 0; c < 8; ++c) acc[c] = (f32x4){0.f, 0.f, 0.f, 0.f};
    const int rsub = lane & 15;
    const int g = lane >> 4;
    const short* xbase = &Xl[(wv * 16 + rsub) * XS + g * 8];
    const short* wbase = &Wl[rsub * XS + g * 8];
    #pragma unroll
    for (int kk = 0; kk < 4; ++kk) {
        bf16x8 a = *(const bf16x8*)(xbase + kk * 32);
        #pragma unroll
        for (int c = 0; c < 8; ++c) {
            bf16x8 bb = *(const bf16x8*)(wbase + c * 16 * XS + kk * 32);
            acc[c] = __builtin_amdgcn_mfma_f32_16x16x32_bf16(a, bb, acc[c], 0, 0, 0);
        }
    }

    // Epilogue: bias + relu + layernorm. C layout: col = 16c + (lane&15), row(in wave tile) = g*4 + r.
    const float* bp = bf  + hop * 128;
    const float* sp = scf + hop * 128;
    const float* op = off + hop * 128;
    float sum[4] = {0.f, 0.f, 0.f, 0.f};
    float ssq[4] = {0.f, 0.f, 0.f, 0.f};
    #pragma unroll
    for (int c = 0; c < 8; ++c) {
        float bias = bp[c * 16 + rsub];
        #pragma unroll
        for (int r = 0; r < 4; ++r) {
            float h = acc[c][r] + bias;
            h = fmaxf(h, 0.0f);
            acc[c][r] = h;
            sum[r] += h;
            ssq[r] += h * h;
        }
    }
    // reduce over the 16 lanes sharing the same g (xor masks 1,2,4,8 stay in-group)
    #pragma unroll
    for (int msk = 1; msk < 16; msk <<= 1) {
        #pragma unroll
        for (int r = 0; r < 4; ++r) {
            sum[r] += __shfl_xor(sum[r], msk);
            ssq[r] += __shfl_xor(ssq[r], msk);
        }
    }
    #pragma unroll
    for (int r = 0; r < 4; ++r) {
        int n = n0 + wv * 16 + g * 4 + r;
        if (n >= N) continue;
        float mean = sum[r] * (1.0f / 128.0f);
        float var = ssq[r] * (1.0f / 128.0f) - mean * mean + EPSV;
        float inv = rsqrtf(var);
        float* orow = out + (long)n * OUT_STRIDE + hop * 128;
        #pragma unroll
        for (int c = 0; c < 8; ++c) {
            int col = c * 16 + rsub;
            orow[col] = (acc[c][r] - mean) * sp[col] * inv + op[col];
        }
    }
}

extern "C" void kernel_launch(void* const* d_in, const int* in_sizes, int n_in,
                              void* d_out, int out_size, void* d_ws, size_t ws_size,
                              hipStream_t stream) {
    const float* features = (const float*)d_in[0];
    const int*   src      = (const int*)d_in[1];
    const int*   dst      = (const int*)d_in[2];
    const float* w        = (const float*)d_in[3];
    const float* Dn       = (const float*)d_in[4];
    const float* W        = (const float*)d_in[5];
    const float* b        = (const float*)d_in[6];
    const float* scale    = (const float*)d_in[7];
    const float* offset   = (const float*)d_in[8];
    float* out = (float*)d_out;
    const int N = in_sizes[0] / 128;
    const int E = in_sizes[1];

    // zero the whole output (cols 128..384 are the atomic accumulators; 0..128 overwritten anyway)
    hipMemsetAsync(out, 0, (size_t)out_size * sizeof(float), stream);

    const int sblocks = 2048;
    // hop 1: agg1[dst] += features[src] * w          -> out cols [128,256)
    scatter_kernel<<<sblocks, 256, 0, stream>>>(features, 128, 0, src, dst, w, Dn, 0, out, 128, E);
    // hop 2: agg2[dst] += (agg1[src]*Dn[src]) * w    -> out cols [256,384)
    scatter_kernel<<<sblocks, 256, 0, stream>>>(out, OUT_STRIDE, 128, src, dst, w, Dn, 1, out, 256, E);

    // fused GEMM+LN for hops 0,1,2 (reads agg regions, overwrites them row-in-place)
    dim3 tg((N + 63) / 64, 3);
    transform_kernel<<<tg, 256, 0, stream>>>(features, Dn, W, b, scale, offset, out, N);
}

// Round 2
// 518.747 us; speedup vs baseline: 5.2837x; 5.2837x over previous
//
#include <hip/hip_runtime.h>
#include <hip/hip_bf16.h>

#define OUT_STRIDE 384
#define EPSV 1e-9f

typedef __attribute__((ext_vector_type(8))) short bf16x8;
typedef __attribute__((ext_vector_type(4))) float f32x4;

static __device__ __forceinline__ short f2bf(float f) {
    __hip_bfloat16 h = __float2bfloat16(f);
    return *reinterpret_cast<short*>(&h);
}

// ================= CSR build =================
__global__ __launch_bounds__(256)
void hist_kernel(const int* __restrict__ dst, int* __restrict__ cnt, int E) {
    int i = blockIdx.x * blockDim.x + threadIdx.x;
    int stride = gridDim.x * blockDim.x;
    for (; i < E; i += stride) atomicAdd(&cnt[dst[i]], 1);
}

__global__ __launch_bounds__(256)
void chunk_sum_kernel(const int* __restrict__ cnt, int* __restrict__ partial, int N) {
    __shared__ int ws4[4];
    int b = blockIdx.x, t = threadIdx.x;
    int i0 = b * 1024 + t * 4;
    int s = 0;
    #pragma unroll
    for (int j = 0; j < 4; ++j) if (i0 + j < N) s += cnt[i0 + j];
    #pragma unroll
    for (int d = 1; d < 64; d <<= 1) s += __shfl_xor(s, d);
    int lane = t & 63, wv = t >> 6;
    if (lane == 0) ws4[wv] = s;
    __syncthreads();
    if (t == 0) partial[b] = ws4[0] + ws4[1] + ws4[2] + ws4[3];
}

// single block; nb <= 256
__global__ __launch_bounds__(256)
void scan_partials_kernel(int* partial, int nb, int* off, int N, int E) {
    int t = threadIdx.x;
    int v = (t < nb) ? partial[t] : 0;
    int lane = t & 63, wv = t >> 6;
    int inc = v;
    #pragma unroll
    for (int d = 1; d < 64; d <<= 1) { int u = __shfl_up(inc, d); if (lane >= d) inc += u; }
    __shared__ int wtot[4];
    if (lane == 63) wtot[wv] = inc;
    __syncthreads();
    int base = 0;
    for (int w2 = 0; w2 < wv; ++w2) base += wtot[w2];
    if (t < nb) partial[t] = base + inc - v;   // exclusive
    if (t == 0) off[N] = E;
}

__global__ __launch_bounds__(256)
void scan_final_kernel(const int* __restrict__ cnt, const int* __restrict__ partial,
                       int* __restrict__ off, int* __restrict__ cur, int N) {
    int b = blockIdx.x, t = threadIdx.x;
    int i0 = b * 1024 + t * 4;
    int c[4]; int s = 0;
    #pragma unroll
    for (int j = 0; j < 4; ++j) { c[j] = (i0 + j < N) ? cnt[i0 + j] : 0; s += c[j]; }
    int lane = t & 63, wv = t >> 6;
    int inc = s;
    #pragma unroll
    for (int d = 1; d < 64; d <<= 1) { int u = __shfl_up(inc, d); if (lane >= d) inc += u; }
    __shared__ int wtot[4];
    if (lane == 63) wtot[wv] = inc;
    __syncthreads();
    int base = partial[b];
    for (int w2 = 0; w2 < wv; ++w2) base += wtot[w2];
    int run = base + inc - s;                  // exclusive across block
    #pragma unroll
    for (int j = 0; j < 4; ++j) {
        if (i0 + j < N) { off[i0 + j] = run; cur[i0 + j] = run; run += c[j]; }
    }
}

__global__ __launch_bounds__(256)
void fill_kernel(const int* __restrict__ src, const int* __restrict__ dst,
                 const float* __restrict__ w, int* __restrict__ cur,
                 int* __restrict__ ssrc, float* __restrict__ sw, int E) {
    int i = blockIdx.x * blockDim.x + threadIdx.x;
    int stride = gridDim.x * blockDim.x;
    for (; i < E; i += stride) {
        int d = dst[i];
        int pos = atomicAdd(&cur[d], 1);
        ssrc[pos] = src[i];
        sw[pos] = w[i];
    }
}

// ================= pull-based aggregation =================
// out[n, ocol0:+128] = Dn[n] * sum_i sw[i] * X[ssrc[i], xcol0:+128]
__global__ __launch_bounds__(256)
void gather_kernel(const float* __restrict__ X, long xstride, long xcol0,
                   const int* __restrict__ off, const int* __restrict__ ssrc,
                   const float* __restrict__ sw, const float* __restrict__ Dn,
                   float* __restrict__ out, long ocol0, int N) {
    const int wv = threadIdx.x >> 6;
    const int lane = threadIdx.x & 63;
    const int n = blockIdx.x * 4 + wv;
    if (n >= N) return;
    const int beg = off[n], end = off[n + 1];
    float2 acc = make_float2(0.f, 0.f);
    const float* Xc = X + xcol0 + 2 * lane;
    int i = beg;
    for (; i + 1 < end; i += 2) {
        int s0 = ssrc[i], s1 = ssrc[i + 1];
        float w0 = sw[i], w1 = sw[i + 1];
        float2 v0 = *(const float2*)(Xc + (long)s0 * xstride);
        float2 v1 = *(const float2*)(Xc + (long)s1 * xstride);
        acc.x += v0.x * w0 + v1.x * w1;
        acc.y += v0.y * w0 + v1.y * w1;
    }
    if (i < end) {
        int s0 = ssrc[i]; float w0 = sw[i];
        float2 v0 = *(const float2*)(Xc + (long)s0 * xstride);
        acc.x += v0.x * w0; acc.y += v0.y * w0;
    }
    const float dn = Dn[n];
    float2* o = (float2*)(out + (long)n * OUT_STRIDE + ocol0 + 2 * lane);
    *o = make_float2(acc.x * dn, acc.y * dn);
}

// ================= legacy push scatter (fallback if ws too small) =================
__global__ __launch_bounds__(256)
void scatter_kernel(const float* X, long xstride, long xcol0,
                    const int* __restrict__ src, const int* __restrict__ dst,
                    const float* __restrict__ w, const float* __restrict__ Dn,
                    int useDn, float* out, long ocol0, int nE)
{
    const int lane = threadIdx.x & 63;
    const int wave = (int)((blockIdx.x * blockDim.x + threadIdx.x) >> 6);
    const int nWaves = (int)((gridDim.x * blockDim.x) >> 6);
    for (int e = wave; e < nE; e += nWaves) {
        const int s = src[e];
        const int d = dst[e];
        float ww = w[e];
        if (useDn) ww *= Dn[s];
        const float2 v = *(const float2*)(X + (long)s * xstride + xcol0 + 2 * lane);
        float* o = out + (long)d * OUT_STRIDE + ocol0 + 2 * lane;
        atomicAdd(o, v.x * ww);
        atomicAdd(o + 1, v.y * ww);
    }
}

// ================= fused GEMM (bf16 MFMA) + bias + ReLU + LayerNorm =================
__global__ __launch_bounds__(256)
void transform_kernel(const float* __restrict__ features,
                      const float* __restrict__ Dn,
                      const float* __restrict__ Wf,
                      const float* __restrict__ bf,
                      const float* __restrict__ scf,
                      const float* __restrict__ off,
                      float* out, int N, int applyDn)
{
    const int hop = blockIdx.y;
    const int tid = threadIdx.x;
    const int lane = tid & 63;
    const int wv = tid >> 6;

    constexpr int XS = 136;
    __shared__ __attribute__((aligned(16))) short Wl[128 * XS];
    __shared__ __attribute__((aligned(16))) short Xl[64 * XS];

    const float4* W4 = (const float4*)(Wf + (long)hop * 128 * 128);
    for (int idx = tid; idx < 128 * 32; idx += 256) {
        float4 v = W4[idx];
        int row = idx >> 5;
        int col = (idx & 31) * 4;
        short* p = &Wl[row * XS + col];
        p[0] = f2bf(v.x); p[1] = f2bf(v.y); p[2] = f2bf(v.z); p[3] = f2bf(v.w);
    }
    const int n0 = blockIdx.x * 64;
    for (int idx = tid; idx < 64 * 32; idx += 256) {
        int r = idx >> 5;
        int col = (idx & 31) * 4;
        int n = n0 + r;
        float4 v = make_float4(0.f, 0.f, 0.f, 0.f);
        float m = 1.0f;
        if (n < N) {
            if (hop == 0) v = *(const float4*)(features + (long)n * 128 + col);
            else {
                v = *(const float4*)(out + (long)n * OUT_STRIDE + hop * 128 + col);
                if (applyDn) m = Dn[n];
            }
        }
        short* p = &Xl[r * XS + col];
        p[0] = f2bf(v.x * m); p[1] = f2bf(v.y * m); p[2] = f2bf(v.z * m); p[3] = f2bf(v.w * m);
    }
    __syncthreads();

    f32x4 acc[8];
    #pragma unroll
    for (int c = 0; c < 8; ++c) acc[c] = (f32x4){0.f, 0.f, 0.f, 0.f};
    const int rsub = lane & 15;
    const int g = lane >> 4;
    const short* xbase = &Xl[(wv * 16 + rsub) * XS + g * 8];
    const short* wbase = &Wl[rsub * XS + g * 8];
    #pragma unroll
    for (int kk = 0; kk < 4; ++kk) {
        bf16x8 a = *(const bf16x8*)(xbase + kk * 32);
        #pragma unroll
        for (int c = 0; c < 8; ++c) {
            bf16x8 bb = *(const bf16x8*)(wbase + c * 16 * XS + kk * 32);
            acc[c] = __builtin_amdgcn_mfma_f32_16x16x32_bf16(a, bb, acc[c], 0, 0, 0);
        }
    }

    const float* bp = bf  + hop * 128;
    const float* sp = scf + hop * 128;
    const float* op = off + hop * 128;
    float sum[4] = {0.f, 0.f, 0.f, 0.f};
    float ssq[4] = {0.f, 0.f, 0.f, 0.f};
    #pragma unroll
    for (int c = 0; c < 8; ++c) {
        float bias = bp[c * 16 + rsub];
        #pragma unroll
        for (int r = 0; r < 4; ++r) {
            float h = acc[c][r] + bias;
            h = fmaxf(h, 0.0f);
            acc[c][r] = h;
            sum[r] += h;
            ssq[r] += h * h;
        }
    }
    #pragma unroll
    for (int msk = 1; msk < 16; msk <<= 1) {
        #pragma unroll
        for (int r = 0; r < 4; ++r) {
            sum[r] += __shfl_xor(sum[r], msk);
            ssq[r] += __shfl_xor(ssq[r], msk);
        }
    }
    #pragma unroll
    for (int r = 0; r < 4; ++r) {
        int n = n0 + wv * 16 + g * 4 + r;
        if (n >= N) continue;
        float mean = sum[r] * (1.0f / 128.0f);
        float var = ssq[r] * (1.0f / 128.0f) - mean * mean + EPSV;
        float inv = rsqrtf(var);
        float* orow = out + (long)n * OUT_STRIDE + hop * 128;
        #pragma unroll
        for (int c = 0; c < 8; ++c) {
            int col = c * 16 + rsub;
            orow[col] = (acc[c][r] - mean) * sp[col] * inv + op[col];
        }
    }
}

extern "C" void kernel_launch(void* const* d_in, const int* in_sizes, int n_in,
                              void* d_out, int out_size, void* d_ws, size_t ws_size,
                              hipStream_t stream) {
    const float* features = (const float*)d_in[0];
    const int*   src      = (const int*)d_in[1];
    const int*   dst      = (const int*)d_in[2];
    const float* w        = (const float*)d_in[3];
    const float* Dn       = (const float*)d_in[4];
    const float* W        = (const float*)d_in[5];
    const float* b        = (const float*)d_in[6];
    const float* scale    = (const float*)d_in[7];
    const float* offset   = (const float*)d_in[8];
    float* out = (float*)d_out;
    const int N = in_sizes[0] / 128;
    const int E = in_sizes[1];
    const int nb = (N + 1023) / 1024;

    // ws layout (4B units): cnt[N] | off[N+1] | cur[N] | ssrc[E] | sw[E] | partial[256]
    const size_t need = ((size_t)3 * N + 1 + 2 * (size_t)E + 256) * 4;

    if (ws_size >= need && nb <= 256) {
        int* cnt     = (int*)d_ws;
        int* off     = cnt + N;
        int* cur     = off + N + 1;
        int* ssrc    = cur + N;
        float* sw    = (float*)(ssrc + E);
        int* partial = (int*)(sw + E);

        hipMemsetAsync(cnt, 0, (size_t)N * 4, stream);
        hist_kernel<<<2048, 256, 0, stream>>>(dst, cnt, E);
        chunk_sum_kernel<<<nb, 256, 0, stream>>>(cnt, partial, N);
        scan_partials_kernel<<<1, 256, 0, stream>>>(partial, nb, off, N, E);
        scan_final_kernel<<<nb, 256, 0, stream>>>(cnt, partial, off, cur, N);
        fill_kernel<<<2048, 256, 0, stream>>>(src, dst, w, cur, ssrc, sw, E);

        // hop 1: h1 = Dn * (sum feat[src]*w)   -> out cols [128,256)
        gather_kernel<<<(N + 3) / 4, 256, 0, stream>>>(features, 128, 0, off, ssrc, sw, Dn, out, 128, N);
        // hop 2: h2 = Dn * (sum h1[src]*w)     -> out cols [256,384)
        gather_kernel<<<(N + 3) / 4, 256, 0, stream>>>(out, OUT_STRIDE, 128, off, ssrc, sw, Dn, out, 256, N);

        dim3 tg((N + 63) / 64, 3);
        transform_kernel<<<tg, 256, 0, stream>>>(features, Dn, W, b, scale, offset, out, N, 0);
    } else {
        // fallback: atomic scatter path (raw agg stored; Dn applied on read)
        hipMemsetAsync(out, 0, (size_t)out_size * sizeof(float), stream);
        scatter_kernel<<<2048, 256, 0, stream>>>(features, 128, 0, src, dst, w, Dn, 0, out, 128, E);
        scatter_kernel<<<2048, 256, 0, stream>>>(out, OUT_STRIDE, 128, src, dst, w, Dn, 1, out, 256, E);
        dim3 tg((N + 63) / 64, 3);
        transform_kernel<<<tg, 256, 0, stream>>>(features, Dn, W, b, scale, offset, out, N, 1);
    }
}

// Round 3
// 515.777 us; speedup vs baseline: 5.3141x; 1.0058x over previous
//
#include <hip/hip_runtime.h>
#include <hip/hip_bf16.h>

#define OUT_STRIDE 384
#define EPSV 1e-9f

typedef __attribute__((ext_vector_type(8))) short bf16x8;
typedef __attribute__((ext_vector_type(4))) float f32x4;

static __device__ __forceinline__ short f2bf(float f) {
    __hip_bfloat16 h = __float2bfloat16(f);
    return *reinterpret_cast<short*>(&h);
}

// ================= CSR build =================
__global__ __launch_bounds__(256)
void hist_kernel(const int* __restrict__ dst, int* __restrict__ cnt, int E) {
    int i = blockIdx.x * blockDim.x + threadIdx.x;
    int stride = gridDim.x * blockDim.x;
    for (; i < E; i += stride) atomicAdd(&cnt[dst[i]], 1);
}

__global__ __launch_bounds__(256)
void chunk_sum_kernel(const int* __restrict__ cnt, int* __restrict__ partial, int N) {
    __shared__ int ws4[4];
    int b = blockIdx.x, t = threadIdx.x;
    int i0 = b * 1024 + t * 4;
    int s = 0;
    #pragma unroll
    for (int j = 0; j < 4; ++j) if (i0 + j < N) s += cnt[i0 + j];
    #pragma unroll
    for (int d = 1; d < 64; d <<= 1) s += __shfl_xor(s, d);
    int lane = t & 63, wv = t >> 6;
    if (lane == 0) ws4[wv] = s;
    __syncthreads();
    if (t == 0) partial[b] = ws4[0] + ws4[1] + ws4[2] + ws4[3];
}

// single block; nb <= 256
__global__ __launch_bounds__(256)
void scan_partials_kernel(int* partial, int nb, int* off, int N, int E) {
    int t = threadIdx.x;
    int v = (t < nb) ? partial[t] : 0;
    int lane = t & 63, wv = t >> 6;
    int inc = v;
    #pragma unroll
    for (int d = 1; d < 64; d <<= 1) { int u = __shfl_up(inc, d); if (lane >= d) inc += u; }
    __shared__ int wtot[4];
    if (lane == 63) wtot[wv] = inc;
    __syncthreads();
    int base = 0;
    for (int w2 = 0; w2 < wv; ++w2) base += wtot[w2];
    if (t < nb) partial[t] = base + inc - v;   // exclusive
    if (t == 0) off[N] = E;
}

__global__ __launch_bounds__(256)
void scan_final_kernel(const int* __restrict__ cnt, const int* __restrict__ partial,
                       int* __restrict__ off, int* __restrict__ cur, int N) {
    int b = blockIdx.x, t = threadIdx.x;
    int i0 = b * 1024 + t * 4;
    int c[4]; int s = 0;
    #pragma unroll
    for (int j = 0; j < 4; ++j) { c[j] = (i0 + j < N) ? cnt[i0 + j] : 0; s += c[j]; }
    int lane = t & 63, wv = t >> 6;
    int inc = s;
    #pragma unroll
    for (int d = 1; d < 64; d <<= 1) { int u = __shfl_up(inc, d); if (lane >= d) inc += u; }
    __shared__ int wtot[4];
    if (lane == 63) wtot[wv] = inc;
    __syncthreads();
    int base = partial[b];
    for (int w2 = 0; w2 < wv; ++w2) base += wtot[w2];
    int run = base + inc - s;                  // exclusive across block
    #pragma unroll
    for (int j = 0; j < 4; ++j) {
        if (i0 + j < N) { off[i0 + j] = run; cur[i0 + j] = run; run += c[j]; }
    }
}

// packed (src, w_bits) records -> one 8B scattered store per edge
__global__ __launch_bounds__(256)
void fill_kernel(const int* __restrict__ src, const int* __restrict__ dst,
                 const float* __restrict__ w, int* __restrict__ cur,
                 int2* __restrict__ ed, int E) {
    int i = blockIdx.x * blockDim.x + threadIdx.x;
    int stride = gridDim.x * blockDim.x;
    for (; i < E; i += stride) {
        int d = dst[i];
        int pos = atomicAdd(&cur[d], 1);
        ed[pos] = make_int2(src[i], __float_as_int(w[i]));
    }
}

// ================= pull-based aggregation =================
// One node per HALF-wave: 32 lanes x float4 = full 128-float row. Unroll 4.
// out[n, ocol0:+128] = Dn[n] * sum_i w[i] * X[src[i], xcol0:+128]
__global__ __launch_bounds__(256)
void gather_kernel(const float* __restrict__ X, long xstride, long xcol0,
                   const int* __restrict__ off, const int2* __restrict__ ed,
                   const float* __restrict__ Dn,
                   float* __restrict__ out, long ocol0, int N) {
    const int tid = threadIdx.x;
    const int half = tid >> 5;         // 0..7 per block
    const int l = tid & 31;
    const int n = blockIdx.x * 8 + half;
    if (n >= N) return;
    const int beg = off[n], end = off[n + 1];
    float4 acc = make_float4(0.f, 0.f, 0.f, 0.f);
    const float* Xc = X + xcol0 + 4 * l;
    int i = beg;
    for (; i + 3 < end; i += 4) {
        int2 e0 = ed[i], e1 = ed[i + 1], e2 = ed[i + 2], e3 = ed[i + 3];
        float4 v0 = *(const float4*)(Xc + (long)e0.x * xstride);
        float4 v1 = *(const float4*)(Xc + (long)e1.x * xstride);
        float4 v2 = *(const float4*)(Xc + (long)e2.x * xstride);
        float4 v3 = *(const float4*)(Xc + (long)e3.x * xstride);
        float w0 = __int_as_float(e0.y), w1 = __int_as_float(e1.y);
        float w2 = __int_as_float(e2.y), w3 = __int_as_float(e3.y);
        acc.x += v0.x * w0 + v1.x * w1 + v2.x * w2 + v3.x * w3;
        acc.y += v0.y * w0 + v1.y * w1 + v2.y * w2 + v3.y * w3;
        acc.z += v0.z * w0 + v1.z * w1 + v2.z * w2 + v3.z * w3;
        acc.w += v0.w * w0 + v1.w * w1 + v2.w * w2 + v3.w * w3;
    }
    for (; i < end; ++i) {
        int2 e0 = ed[i];
        float w0 = __int_as_float(e0.y);
        float4 v0 = *(const float4*)(Xc + (long)e0.x * xstride);
        acc.x += v0.x * w0; acc.y += v0.y * w0;
        acc.z += v0.z * w0; acc.w += v0.w * w0;
    }
    const float dn = Dn[n];
    float4* o = (float4*)(out + (long)n * OUT_STRIDE + ocol0 + 4 * l);
    *o = make_float4(acc.x * dn, acc.y * dn, acc.z * dn, acc.w * dn);
}

// ================= legacy push scatter (fallback if ws too small) =================
__global__ __launch_bounds__(256)
void scatter_kernel(const float* X, long xstride, long xcol0,
                    const int* __restrict__ src, const int* __restrict__ dst,
                    const float* __restrict__ w, const float* __restrict__ Dn,
                    int useDn, float* out, long ocol0, int nE)
{
    const int lane = threadIdx.x & 63;
    const int wave = (int)((blockIdx.x * blockDim.x + threadIdx.x) >> 6);
    const int nWaves = (int)((gridDim.x * blockDim.x) >> 6);
    for (int e = wave; e < nE; e += nWaves) {
        const int s = src[e];
        const int d = dst[e];
        float ww = w[e];
        if (useDn) ww *= Dn[s];
        const float2 v = *(const float2*)(X + (long)s * xstride + xcol0 + 2 * lane);
        float* o = out + (long)d * OUT_STRIDE + ocol0 + 2 * lane;
        atomicAdd(o, v.x * ww);
        atomicAdd(o + 1, v.y * ww);
    }
}

// ================= fused GEMM (bf16 MFMA) + bias + ReLU + LayerNorm =================
__global__ __launch_bounds__(256)
void transform_kernel(const float* __restrict__ features,
                      const float* __restrict__ Dn,
                      const float* __restrict__ Wf,
                      const float* __restrict__ bf,
                      const float* __restrict__ scf,
                      const float* __restrict__ off,
                      float* out, int N, int applyDn)
{
    const int hop = blockIdx.y;
    const int tid = threadIdx.x;
    const int lane = tid & 63;
    const int wv = tid >> 6;

    constexpr int XS = 136;
    __shared__ __attribute__((aligned(16))) short Wl[128 * XS];
    __shared__ __attribute__((aligned(16))) short Xl[64 * XS];

    const float4* W4 = (const float4*)(Wf + (long)hop * 128 * 128);
    for (int idx = tid; idx < 128 * 32; idx += 256) {
        float4 v = W4[idx];
        int row = idx >> 5;
        int col = (idx & 31) * 4;
        short* p = &Wl[row * XS + col];
        p[0] = f2bf(v.x); p[1] = f2bf(v.y); p[2] = f2bf(v.z); p[3] = f2bf(v.w);
    }
    const int n0 = blockIdx.x * 64;
    for (int idx = tid; idx < 64 * 32; idx += 256) {
        int r = idx >> 5;
        int col = (idx & 31) * 4;
        int n = n0 + r;
        float4 v = make_float4(0.f, 0.f, 0.f, 0.f);
        float m = 1.0f;
        if (n < N) {
            if (hop == 0) v = *(const float4*)(features + (long)n * 128 + col);
            else {
                v = *(const float4*)(out + (long)n * OUT_STRIDE + hop * 128 + col);
                if (applyDn) m = Dn[n];
            }
        }
        short* p = &Xl[r * XS + col];
        p[0] = f2bf(v.x * m); p[1] = f2bf(v.y * m); p[2] = f2bf(v.z * m); p[3] = f2bf(v.w * m);
    }
    __syncthreads();

    f32x4 acc[8];
    #pragma unroll
    for (int c = 0; c < 8; ++c) acc[c] = (f32x4){0.f, 0.f, 0.f, 0.f};
    const int rsub = lane & 15;
    const int g = lane >> 4;
    const short* xbase = &Xl[(wv * 16 + rsub) * XS + g * 8];
    const short* wbase = &Wl[rsub * XS + g * 8];
    #pragma unroll
    for (int kk = 0; kk < 4; ++kk) {
        bf16x8 a = *(const bf16x8*)(xbase + kk * 32);
        #pragma unroll
        for (int c = 0; c < 8; ++c) {
            bf16x8 bb = *(const bf16x8*)(wbase + c * 16 * XS + kk * 32);
            acc[c] = __builtin_amdgcn_mfma_f32_16x16x32_bf16(a, bb, acc[c], 0, 0, 0);
        }
    }

    const float* bp = bf  + hop * 128;
    const float* sp = scf + hop * 128;
    const float* op = off + hop * 128;
    float sum[4] = {0.f, 0.f, 0.f, 0.f};
    float ssq[4] = {0.f, 0.f, 0.f, 0.f};
    #pragma unroll
    for (int c = 0; c < 8; ++c) {
        float bias = bp[c * 16 + rsub];
        #pragma unroll
        for (int r = 0; r < 4; ++r) {
            float h = acc[c][r] + bias;
            h = fmaxf(h, 0.0f);
            acc[c][r] = h;
            sum[r] += h;
            ssq[r] += h * h;
        }
    }
    #pragma unroll
    for (int msk = 1; msk < 16; msk <<= 1) {
        #pragma unroll
        for (int r = 0; r < 4; ++r) {
            sum[r] += __shfl_xor(sum[r], msk);
            ssq[r] += __shfl_xor(ssq[r], msk);
        }
    }
    #pragma unroll
    for (int r = 0; r < 4; ++r) {
        int n = n0 + wv * 16 + g * 4 + r;
        if (n >= N) continue;
        float mean = sum[r] * (1.0f / 128.0f);
        float var = ssq[r] * (1.0f / 128.0f) - mean * mean + EPSV;
        float inv = rsqrtf(var);
        float* orow = out + (long)n * OUT_STRIDE + hop * 128;
        #pragma unroll
        for (int c = 0; c < 8; ++c) {
            int col = c * 16 + rsub;
            orow[col] = (acc[c][r] - mean) * sp[col] * inv + op[col];
        }
    }
}

extern "C" void kernel_launch(void* const* d_in, const int* in_sizes, int n_in,
                              void* d_out, int out_size, void* d_ws, size_t ws_size,
                              hipStream_t stream) {
    const float* features = (const float*)d_in[0];
    const int*   src      = (const int*)d_in[1];
    const int*   dst      = (const int*)d_in[2];
    const float* w        = (const float*)d_in[3];
    const float* Dn       = (const float*)d_in[4];
    const float* W        = (const float*)d_in[5];
    const float* b        = (const float*)d_in[6];
    const float* scale    = (const float*)d_in[7];
    const float* offset   = (const float*)d_in[8];
    float* out = (float*)d_out;
    const int N = in_sizes[0] / 128;
    const int E = in_sizes[1];
    const int nb = (N + 1023) / 1024;

    // ws layout (4B units): cnt[N] | off[N+1] | cur[N] | ed[2E] | partial[256]
    const size_t need = ((size_t)3 * N + 1 + 2 * (size_t)E + 256) * 4;

    if (ws_size >= need && nb <= 256) {
        int* cnt     = (int*)d_ws;
        int* off     = cnt + N;
        int* cur     = off + N + 1;
        int2* ed     = (int2*)(cur + N);
        int* partial = (int*)(ed + E);

        hipMemsetAsync(cnt, 0, (size_t)N * 4, stream);
        hist_kernel<<<2048, 256, 0, stream>>>(dst, cnt, E);
        chunk_sum_kernel<<<nb, 256, 0, stream>>>(cnt, partial, N);
        scan_partials_kernel<<<1, 256, 0, stream>>>(partial, nb, off, N, E);
        scan_final_kernel<<<nb, 256, 0, stream>>>(cnt, partial, off, cur, N);
        fill_kernel<<<2048, 256, 0, stream>>>(src, dst, w, cur, ed, E);

        // hop 1: h1 = Dn * (sum feat[src]*w)   -> out cols [128,256)
        gather_kernel<<<(N + 7) / 8, 256, 0, stream>>>(features, 128, 0, off, ed, Dn, out, 128, N);
        // hop 2: h2 = Dn * (sum h1[src]*w)     -> out cols [256,384)
        gather_kernel<<<(N + 7) / 8, 256, 0, stream>>>(out, OUT_STRIDE, 128, off, ed, Dn, out, 256, N);

        dim3 tg((N + 63) / 64, 3);
        transform_kernel<<<tg, 256, 0, stream>>>(features, Dn, W, b, scale, offset, out, N, 0);
    } else {
        // fallback: atomic scatter path (raw agg stored; Dn applied on read)
        hipMemsetAsync(out, 0, (size_t)out_size * sizeof(float), stream);
        scatter_kernel<<<2048, 256, 0, stream>>>(features, 128, 0, src, dst, w, Dn, 0, out, 128, E);
        scatter_kernel<<<2048, 256, 0, stream>>>(out, OUT_STRIDE, 128, src, dst, w, Dn, 1, out, 256, E);
        dim3 tg((N + 63) / 64, 3);
        transform_kernel<<<tg, 256, 0, stream>>>(features, Dn, W, b, scale, offset, out, N, 1);
    }
}

// Round 4
// 475.082 us; speedup vs baseline: 5.7693x; 1.0857x over previous
//
#include <hip/hip_runtime.h>
#include <hip/hip_bf16.h>

#define OUT_STRIDE 384
#define EPSV 1e-9f

typedef __attribute__((ext_vector_type(8))) short bf16x8;
typedef __attribute__((ext_vector_type(4))) float f32x4;

static __device__ __forceinline__ unsigned short f2bf(float f) {
    __hip_bfloat16 h = __float2bfloat16(f);
    return *reinterpret_cast<unsigned short*>(&h);
}

// ================= CSR build =================
__global__ __launch_bounds__(256)
void hist_kernel(const int* __restrict__ dst, int* __restrict__ cnt, int E) {
    int i = blockIdx.x * blockDim.x + threadIdx.x;
    int stride = gridDim.x * blockDim.x;
    for (; i < E; i += stride) atomicAdd(&cnt[dst[i]], 1);
}

__global__ __launch_bounds__(256)
void chunk_sum_kernel(const int* __restrict__ cnt, int* __restrict__ partial, int N) {
    __shared__ int ws4[4];
    int b = blockIdx.x, t = threadIdx.x;
    int i0 = b * 1024 + t * 4;
    int s = 0;
    #pragma unroll
    for (int j = 0; j < 4; ++j) if (i0 + j < N) s += cnt[i0 + j];
    #pragma unroll
    for (int d = 1; d < 64; d <<= 1) s += __shfl_xor(s, d);
    int lane = t & 63, wv = t >> 6;
    if (lane == 0) ws4[wv] = s;
    __syncthreads();
    if (t == 0) partial[b] = ws4[0] + ws4[1] + ws4[2] + ws4[3];
}

// single block; nb <= 256
__global__ __launch_bounds__(256)
void scan_partials_kernel(int* partial, int nb, int* off, int N, int E) {
    int t = threadIdx.x;
    int v = (t < nb) ? partial[t] : 0;
    int lane = t & 63, wv = t >> 6;
    int inc = v;
    #pragma unroll
    for (int d = 1; d < 64; d <<= 1) { int u = __shfl_up(inc, d); if (lane >= d) inc += u; }
    __shared__ int wtot[4];
    if (lane == 63) wtot[wv] = inc;
    __syncthreads();
    int base = 0;
    for (int w2 = 0; w2 < wv; ++w2) base += wtot[w2];
    if (t < nb) partial[t] = base + inc - v;   // exclusive
    if (t == 0) off[N] = E;
}

__global__ __launch_bounds__(256)
void scan_final_kernel(const int* __restrict__ cnt, const int* __restrict__ partial,
                       int* __restrict__ off, int* __restrict__ cur, int N) {
    int b = blockIdx.x, t = threadIdx.x;
    int i0 = b * 1024 + t * 4;
    int c[4]; int s = 0;
    #pragma unroll
    for (int j = 0; j < 4; ++j) { c[j] = (i0 + j < N) ? cnt[i0 + j] : 0; s += c[j]; }
    int lane = t & 63, wv = t >> 6;
    int inc = s;
    #pragma unroll
    for (int d = 1; d < 64; d <<= 1) { int u = __shfl_up(inc, d); if (lane >= d) inc += u; }
    __shared__ int wtot[4];
    if (lane == 63) wtot[wv] = inc;
    __syncthreads();
    int base = partial[b];
    for (int w2 = 0; w2 < wv; ++w2) base += wtot[w2];
    int run = base + inc - s;                  // exclusive across block
    #pragma unroll
    for (int j = 0; j < 4; ++j) {
        if (i0 + j < N) { off[i0 + j] = run; cur[i0 + j] = run; run += c[j]; }
    }
}

// packed (src, w_bits) -> one 8B nontemporal scattered store per edge
__global__ __launch_bounds__(256)
void fill_kernel(const int* __restrict__ src, const int* __restrict__ dst,
                 const float* __restrict__ w, int* __restrict__ cur,
                 int2* __restrict__ ed, int E) {
    int i = blockIdx.x * blockDim.x + threadIdx.x;
    int stride = gridDim.x * blockDim.x;
    for (; i < E; i += stride) {
        int d = dst[i];
        int pos = atomicAdd(&cur[d], 1);
        long v = ((long)(unsigned)__float_as_int(w[i]) << 32) | (unsigned)src[i];
        __builtin_nontemporal_store(v, (long*)&ed[pos]);
    }
}

// ================= f32 -> bf16 row pack =================
__global__ __launch_bounds__(256)
void pack_kernel(const float* __restrict__ in, unsigned short* __restrict__ outb, long n4) {
    long i = blockIdx.x * blockDim.x + threadIdx.x;
    long stride = (long)gridDim.x * blockDim.x;
    for (; i < n4; i += stride) {
        float4 v = ((const float4*)in)[i];
        ushort4 o;
        o.x = f2bf(v.x); o.y = f2bf(v.y); o.z = f2bf(v.z); o.w = f2bf(v.w);
        *(ushort4*)&outb[i * 4] = o;
    }
}

// ================= pull aggregation, bf16-input rows (256B) =================
// One node per 16-lane quarter; lane covers 8 cols via int4 (8 bf16). Unroll 4.
// result = Dn[n] * sum w_e * X[src_e];  written as bf16 row (outb) or f32 to outf+ocol.
__device__ __forceinline__ void acc8(float* a, int4 r, float w) {
    #pragma unroll
    for (int j = 0; j < 4; ++j) {
        int bits = (&r.x)[j];
        float f0 = __int_as_float(bits << 16);
        float f1 = __int_as_float(bits & 0xffff0000);
        a[2 * j]     += f0 * w;
        a[2 * j + 1] += f1 * w;
    }
}

__global__ __launch_bounds__(256)
void gather_bf16in(const unsigned short* __restrict__ X,
                   const int* __restrict__ off, const int2* __restrict__ ed,
                   const float* __restrict__ Dn,
                   unsigned short* __restrict__ outb,
                   float* __restrict__ outf, long ocol0, int N) {
    const int tid = threadIdx.x;
    const int l = tid & 15;
    const int n = blockIdx.x * 16 + (tid >> 4);
    if (n >= N) return;
    const int beg = off[n], end = off[n + 1];
    float a[8] = {0.f, 0.f, 0.f, 0.f, 0.f, 0.f, 0.f, 0.f};
    const unsigned short* Xc = X + 8 * l;
    int i = beg;
    for (; i + 3 < end; i += 4) {
        int2 e0 = ed[i], e1 = ed[i + 1], e2 = ed[i + 2], e3 = ed[i + 3];
        int4 r0 = *(const int4*)(Xc + (long)e0.x * 128);
        int4 r1 = *(const int4*)(Xc + (long)e1.x * 128);
        int4 r2 = *(const int4*)(Xc + (long)e2.x * 128);
        int4 r3 = *(const int4*)(Xc + (long)e3.x * 128);
        acc8(a, r0, __int_as_float(e0.y));
        acc8(a, r1, __int_as_float(e1.y));
        acc8(a, r2, __int_as_float(e2.y));
        acc8(a, r3, __int_as_float(e3.y));
    }
    for (; i < end; ++i) {
        int2 e0 = ed[i];
        int4 r0 = *(const int4*)(Xc + (long)e0.x * 128);
        acc8(a, r0, __int_as_float(e0.y));
    }
    const float dn = Dn[n];
    #pragma unroll
    for (int j = 0; j < 8; ++j) a[j] *= dn;
    if (outb) {
        int4 o;
        #pragma unroll
        for (int j = 0; j < 4; ++j) {
            unsigned lo = f2bf(a[2 * j]);
            unsigned hi = f2bf(a[2 * j + 1]);
            (&o.x)[j] = (int)((hi << 16) | lo);
        }
        *(int4*)&outb[(long)n * 128 + 8 * l] = o;
    } else {
        float* p = outf + (long)n * OUT_STRIDE + ocol0 + 8 * l;
        *(float4*)p       = make_float4(a[0], a[1], a[2], a[3]);
        *(float4*)(p + 4) = make_float4(a[4], a[5], a[6], a[7]);
    }
}

// ================= pull aggregation, f32-input rows (tier C) =================
__global__ __launch_bounds__(256)
void gather_kernel(const float* __restrict__ X, long xstride, long xcol0,
                   const int* __restrict__ off, const int2* __restrict__ ed,
                   const float* __restrict__ Dn,
                   float* __restrict__ out, long ocol0, int N) {
    const int tid = threadIdx.x;
    const int half = tid >> 5;
    const int l = tid & 31;
    const int n = blockIdx.x * 8 + half;
    if (n >= N) return;
    const int beg = off[n], end = off[n + 1];
    float4 acc = make_float4(0.f, 0.f, 0.f, 0.f);
    const float* Xc = X + xcol0 + 4 * l;
    int i = beg;
    for (; i + 3 < end; i += 4) {
        int2 e0 = ed[i], e1 = ed[i + 1], e2 = ed[i + 2], e3 = ed[i + 3];
        float4 v0 = *(const float4*)(Xc + (long)e0.x * xstride);
        float4 v1 = *(const float4*)(Xc + (long)e1.x * xstride);
        float4 v2 = *(const float4*)(Xc + (long)e2.x * xstride);
        float4 v3 = *(const float4*)(Xc + (long)e3.x * xstride);
        float w0 = __int_as_float(e0.y), w1 = __int_as_float(e1.y);
        float w2 = __int_as_float(e2.y), w3 = __int_as_float(e3.y);
        acc.x += v0.x * w0 + v1.x * w1 + v2.x * w2 + v3.x * w3;
        acc.y += v0.y * w0 + v1.y * w1 + v2.y * w2 + v3.y * w3;
        acc.z += v0.z * w0 + v1.z * w1 + v2.z * w2 + v3.z * w3;
        acc.w += v0.w * w0 + v1.w * w1 + v2.w * w2 + v3.w * w3;
    }
    for (; i < end; ++i) {
        int2 e0 = ed[i];
        float w0 = __int_as_float(e0.y);
        float4 v0 = *(const float4*)(Xc + (long)e0.x * xstride);
        acc.x += v0.x * w0; acc.y += v0.y * w0;
        acc.z += v0.z * w0; acc.w += v0.w * w0;
    }
    const float dn = Dn[n];
    float4* o = (float4*)(out + (long)n * OUT_STRIDE + ocol0 + 4 * l);
    *o = make_float4(acc.x * dn, acc.y * dn, acc.z * dn, acc.w * dn);
}

// ================= legacy push scatter (fallback) =================
__global__ __launch_bounds__(256)
void scatter_kernel(const float* X, long xstride, long xcol0,
                    const int* __restrict__ src, const int* __restrict__ dst,
                    const float* __restrict__ w, const float* __restrict__ Dn,
                    int useDn, float* out, long ocol0, int nE)
{
    const int lane = threadIdx.x & 63;
    const int wave = (int)((blockIdx.x * blockDim.x + threadIdx.x) >> 6);
    const int nWaves = (int)((gridDim.x * blockDim.x) >> 6);
    for (int e = wave; e < nE; e += nWaves) {
        const int s = src[e];
        const int d = dst[e];
        float ww = w[e];
        if (useDn) ww *= Dn[s];
        const float2 v = *(const float2*)(X + (long)s * xstride + xcol0 + 2 * lane);
        float* o = out + (long)d * OUT_STRIDE + ocol0 + 2 * lane;
        atomicAdd(o, v.x * ww);
        atomicAdd(o + 1, v.y * ww);
    }
}

// ================= fused GEMM (bf16 MFMA) + bias + ReLU + LayerNorm =================
// Per-hop source descriptor: pointer + fmt (1 = bf16 row of 128, 0 = f32 rows of stride s) 
__global__ __launch_bounds__(256)
void transform_kernel(const void* x0, int f0, long s0,
                      const void* x1, int f1, long s1,
                      const void* x2, int f2, long s2,
                      const float* __restrict__ Dn,
                      const float* __restrict__ Wf,
                      const float* __restrict__ bf,
                      const float* __restrict__ scf,
                      const float* __restrict__ off,
                      float* out, int N, int applyDn)
{
    const int hop = blockIdx.y;
    const int tid = threadIdx.x;
    const int lane = tid & 63;
    const int wv = tid >> 6;

    constexpr int XS = 136;
    __shared__ __attribute__((aligned(16))) short Wl[128 * XS];
    __shared__ __attribute__((aligned(16))) short Xl[64 * XS];

    const float4* W4 = (const float4*)(Wf + (long)hop * 128 * 128);
    for (int idx = tid; idx < 128 * 32; idx += 256) {
        float4 v = W4[idx];
        int row = idx >> 5;
        int col = (idx & 31) * 4;
        short* p = &Wl[row * XS + col];
        p[0] = f2bf(v.x); p[1] = f2bf(v.y); p[2] = f2bf(v.z); p[3] = f2bf(v.w);
    }
    const void* xp = (hop == 0) ? x0 : (hop == 1) ? x1 : x2;
    const int fmt  = (hop == 0) ? f0 : (hop == 1) ? f1 : f2;
    const long xs  = (hop == 0) ? s0 : (hop == 1) ? s1 : s2;
    const int n0 = blockIdx.x * 64;
    if (fmt) {
        const unsigned short* xb = (const unsigned short*)xp;
        for (int idx = tid; idx < 64 * 16; idx += 256) {
            int r = idx >> 4;
            int c = (idx & 15) * 8;
            int n = n0 + r;
            int4 v = make_int4(0, 0, 0, 0);
            if (n < N) v = *(const int4*)(xb + (long)n * xs + c);
            *(int4*)&Xl[r * XS + c] = v;
        }
    } else {
        const float* xf = (const float*)xp;
        for (int idx = tid; idx < 64 * 32; idx += 256) {
            int r = idx >> 5;
            int col = (idx & 31) * 4;
            int n = n0 + r;
            float4 v = make_float4(0.f, 0.f, 0.f, 0.f);
            float m = 1.0f;
            if (n < N) {
                v = *(const float4*)(xf + (long)n * xs + col);
                if (applyDn && hop > 0) m = Dn[n];
            }
            short* p = &Xl[r * XS + col];
            p[0] = f2bf(v.x * m); p[1] = f2bf(v.y * m); p[2] = f2bf(v.z * m); p[3] = f2bf(v.w * m);
        }
    }
    __syncthreads();

    f32x4 acc[8];
    #pragma unroll
    for (int c = 0; c < 8; ++c) acc[c] = (f32x4){0.f, 0.f, 0.f, 0.f};
    const int rsub = lane & 15;
    const int g = lane >> 4;
    const short* xbase = &Xl[(wv * 16 + rsub) * XS + g * 8];
    const short* wbase = &Wl[rsub * XS + g * 8];
    #pragma unroll
    for (int kk = 0; kk < 4; ++kk) {
        bf16x8 a = *(const bf16x8*)(xbase + kk * 32);
        #pragma unroll
        for (int c = 0; c < 8; ++c) {
            bf16x8 bb = *(const bf16x8*)(wbase + c * 16 * XS + kk * 32);
            acc[c] = __builtin_amdgcn_mfma_f32_16x16x32_bf16(a, bb, acc[c], 0, 0, 0);
        }
    }

    const float* bp = bf  + hop * 128;
    const float* sp = scf + hop * 128;
    const float* op = off + hop * 128;
    float sum[4] = {0.f, 0.f, 0.f, 0.f};
    float ssq[4] = {0.f, 0.f, 0.f, 0.f};
    #pragma unroll
    for (int c = 0; c < 8; ++c) {
        float bias = bp[c * 16 + rsub];
        #pragma unroll
        for (int r = 0; r < 4; ++r) {
            float h = acc[c][r] + bias;
            h = fmaxf(h, 0.0f);
            acc[c][r] = h;
            sum[r] += h;
            ssq[r] += h * h;
        }
    }
    #pragma unroll
    for (int msk = 1; msk < 16; msk <<= 1) {
        #pragma unroll
        for (int r = 0; r < 4; ++r) {
            sum[r] += __shfl_xor(sum[r], msk);
            ssq[r] += __shfl_xor(ssq[r], msk);
        }
    }
    #pragma unroll
    for (int r = 0; r < 4; ++r) {
        int n = n0 + wv * 16 + g * 4 + r;
        if (n >= N) continue;
        float mean = sum[r] * (1.0f / 128.0f);
        float var = ssq[r] * (1.0f / 128.0f) - mean * mean + EPSV;
        float inv = rsqrtf(var);
        float* orow = out + (long)n * OUT_STRIDE + hop * 128;
        #pragma unroll
        for (int c = 0; c < 8; ++c) {
            int col = c * 16 + rsub;
            orow[col] = (acc[c][r] - mean) * sp[col] * inv + op[col];
        }
    }
}

extern "C" void kernel_launch(void* const* d_in, const int* in_sizes, int n_in,
                              void* d_out, int out_size, void* d_ws, size_t ws_size,
                              hipStream_t stream) {
    const float* features = (const float*)d_in[0];
    const int*   src      = (const int*)d_in[1];
    const int*   dst      = (const int*)d_in[2];
    const float* w        = (const float*)d_in[3];
    const float* Dn       = (const float*)d_in[4];
    const float* W        = (const float*)d_in[5];
    const float* b        = (const float*)d_in[6];
    const float* scale    = (const float*)d_in[7];
    const float* offset   = (const float*)d_in[8];
    float* out = (float*)d_out;
    const int N = in_sizes[0] / 128;
    const int E = in_sizes[1];
    const int nb = (N + 1023) / 1024;

    // ws layout (ints): cnt[N] | off[N+1] | cur[N] | ed[2E] | partial[256] | featb[64N] | h1b[64N]
    const size_t base_ints = (size_t)3 * N + 1 + 2 * (size_t)E + 256;
    const size_t need_C = base_ints * 4;
    const size_t need_A = (base_ints + (size_t)128 * N) * 4;
    dim3 tg((N + 63) / 64, 3);

    if (ws_size >= need_C && nb <= 256) {
        int* cnt     = (int*)d_ws;
        int* off     = cnt + N;
        int* cur     = off + N + 1;
        int2* ed     = (int2*)(cur + N);
        int* partial = (int*)(ed + E);

        hipMemsetAsync(cnt, 0, (size_t)N * 4, stream);
        hist_kernel<<<2048, 256, 0, stream>>>(dst, cnt, E);
        chunk_sum_kernel<<<nb, 256, 0, stream>>>(cnt, partial, N);
        scan_partials_kernel<<<1, 256, 0, stream>>>(partial, nb, off, N, E);
        scan_final_kernel<<<nb, 256, 0, stream>>>(cnt, partial, off, cur, N);
        fill_kernel<<<2048, 256, 0, stream>>>(src, dst, w, cur, ed, E);

        if (ws_size >= need_A) {
            unsigned short* featb = (unsigned short*)(partial + 256);
            unsigned short* h1b   = featb + (size_t)N * 128;

            pack_kernel<<<2048, 256, 0, stream>>>(features, featb, (long)N * 32);
            // hop1: h1b = bf16( Dn * sum featb[src]*w )
            gather_bf16in<<<(N + 15) / 16, 256, 0, stream>>>(featb, off, ed, Dn, h1b, nullptr, 0, N);
            // hop2: out[:,256:384) = f32( Dn * sum h1b[src]*w )
            gather_bf16in<<<(N + 15) / 16, 256, 0, stream>>>(h1b, off, ed, Dn, nullptr, out, 256, N);

            transform_kernel<<<tg, 256, 0, stream>>>(
                featb, 1, 128, h1b, 1, 128, out + 256, 0, OUT_STRIDE,
                Dn, W, b, scale, offset, out, N, 0);
        } else {
            // tier C: f32 gathers into out regions
            gather_kernel<<<(N + 7) / 8, 256, 0, stream>>>(features, 128, 0, off, ed, Dn, out, 128, N);
            gather_kernel<<<(N + 7) / 8, 256, 0, stream>>>(out, OUT_STRIDE, 128, off, ed, Dn, out, 256, N);
            transform_kernel<<<tg, 256, 0, stream>>>(
                features, 0, 128, out + 128, 0, OUT_STRIDE, out + 256, 0, OUT_STRIDE,
                Dn, W, b, scale, offset, out, N, 0);
        }
    } else {
        // fallback: atomic scatter path (raw agg stored; Dn applied on read)
        hipMemsetAsync(out, 0, (size_t)out_size * sizeof(float), stream);
        scatter_kernel<<<2048, 256, 0, stream>>>(features, 128, 0, src, dst, w, Dn, 0, out, 128, E);
        scatter_kernel<<<2048, 256, 0, stream>>>(out, OUT_STRIDE, 128, src, dst, w, Dn, 1, out, 256, E);
        transform_kernel<<<tg, 256, 0, stream>>>(
            features, 0, 128, out + 128, 0, OUT_STRIDE, out + 256, 0, OUT_STRIDE,
            Dn, W, b, scale, offset, out, N, 1);
    }
}

// Round 5
// 360.193 us; speedup vs baseline: 7.6095x; 1.3190x over previous
//
#include <hip/hip_runtime.h>
#include <hip/hip_bf16.h>

#define OUT_STRIDE 384
#define EPSV 1e-9f
#define BSH 10
#define BS 1024            // nodes per bucket
#define NBMAX 512
#define CH 4096            // edges per multisplit chunk

typedef __attribute__((ext_vector_type(8))) short bf16x8;
typedef __attribute__((ext_vector_type(4))) float f32x4;

static __device__ __forceinline__ unsigned short f2bf(float f) {
    __hip_bfloat16 h = __float2bfloat16(f);
    return *reinterpret_cast<unsigned short*>(&h);
}

// ---------------- pass 1: bucket histogram ----------------
__global__ __launch_bounds__(256)
void bhist_kernel(const int* __restrict__ dst, int* __restrict__ bcnt, int E, int NB) {
    __shared__ int h[NBMAX];
    for (int i = threadIdx.x; i < NBMAX; i += 256) h[i] = 0;
    __syncthreads();
    int i = blockIdx.x * blockDim.x + threadIdx.x;
    int stride = gridDim.x * blockDim.x;
    for (; i < E; i += stride) atomicAdd(&h[dst[i] >> BSH], 1);
    __syncthreads();
    for (int j = threadIdx.x; j < NB; j += 256)
        if (h[j]) atomicAdd(&bcnt[j], h[j]);
}

// ---------------- pass 2: bucket scan (1 WG) ----------------
__global__ __launch_bounds__(256)
void bscan_kernel(const int* __restrict__ bcnt, int* __restrict__ bbase,
                  int* __restrict__ bcur, int* __restrict__ off,
                  int NB, int N, int E) {
    const int t = threadIdx.x;
    const int lane = t & 63, wv = t >> 6;
    int b0 = 2 * t, b1 = 2 * t + 1;
    int c0 = (b0 < NB) ? bcnt[b0] : 0;
    int c1 = (b1 < NB) ? bcnt[b1] : 0;
    int s = c0 + c1;
    int inc = s;
    #pragma unroll
    for (int d = 1; d < 64; d <<= 1) { int u = __shfl_up(inc, d); if (lane >= d) inc += u; }
    __shared__ int wt[4];
    if (lane == 63) wt[wv] = inc;
    __syncthreads();
    int base = 0;
    for (int w2 = 0; w2 < wv; ++w2) base += wt[w2];
    int ex = base + inc - s;
    if (b0 < NB) { bbase[b0] = ex;      bcur[b0] = ex; }
    if (b1 < NB) { bbase[b1] = ex + c0; bcur[b1] = ex + c0; }
    if (t == 0) { bbase[NB] = E; off[N] = E; }
}

// ---------------- pass 3: LDS-staged multisplit ----------------
__global__ __launch_bounds__(256)
void multisplit_kernel(const int* __restrict__ src, const int* __restrict__ dst,
                       const float* __restrict__ w, int* __restrict__ bcur,
                       int* __restrict__ rec, int E) {
    __shared__ int hist[NBMAX], scan_[NBMAX], gbase[NBMAX], lcur[NBMAX];
    __shared__ int recS[CH * 3];
    __shared__ int wt[4];
    const int t = threadIdx.x;
    const int lane = t & 63, wv = t >> 6;
    const int c0 = blockIdx.x * CH;
    const int cnt_total = min(CH, E - c0);

    for (int i = t; i < NBMAX; i += 256) hist[i] = 0;
    __syncthreads();
    #pragma unroll
    for (int p = 0; p < CH / 256; ++p) {
        int i = c0 + p * 256 + t;
        if (i < E) atomicAdd(&hist[dst[i] >> BSH], 1);
    }
    __syncthreads();
    // exclusive scan of hist[0..511] (2 per thread)
    {
        int b0 = 2 * t, b1 = 2 * t + 1;
        int h0 = hist[b0], h1 = hist[b1];
        int s = h0 + h1;
        int inc = s;
        #pragma unroll
        for (int d = 1; d < 64; d <<= 1) { int u = __shfl_up(inc, d); if (lane >= d) inc += u; }
        if (lane == 63) wt[wv] = inc;
        __syncthreads();
        int base = 0;
        for (int w2 = 0; w2 < wv; ++w2) base += wt[w2];
        int ex = base + inc - s;
        scan_[b0] = ex;
        scan_[b1] = ex + h0;
    }
    __syncthreads();
    for (int i = t; i < NBMAX; i += 256) {
        if (hist[i] > 0) gbase[i] = atomicAdd(&bcur[i], hist[i]);
        lcur[i] = scan_[i];
    }
    __syncthreads();
    #pragma unroll
    for (int p = 0; p < CH / 256; ++p) {
        int i = c0 + p * 256 + t;
        if (i < E) {
            int d = dst[i];
            int b = d >> BSH;
            int j = atomicAdd(&lcur[b], 1);
            recS[3 * j]     = src[i];
            recS[3 * j + 1] = d;
            recS[3 * j + 2] = __float_as_int(w[i]);
        }
    }
    __syncthreads();
    #pragma unroll
    for (int p = 0; p < CH / 256; ++p) {
        int j = p * 256 + t;
        if (j < cnt_total) {
            int d = recS[3 * j + 1];
            int b = d >> BSH;
            int g = gbase[b] + (j - scan_[b]);
            rec[3 * g]     = recS[3 * j];
            rec[3 * g + 1] = d;
            rec[3 * g + 2] = recS[3 * j + 2];
        }
    }
}

// ---------------- pass 4: per-bucket CSR build (LDS cursors) ----------------
__global__ __launch_bounds__(256)
void bucket_csr_kernel(const int* __restrict__ rec, const int* __restrict__ bbase,
                       int* __restrict__ off, int2* __restrict__ ed, int N) {
    __shared__ int h[BS];
    __shared__ int wt[4];
    const int b = blockIdx.x;
    const int t = threadIdx.x;
    const int lane = t & 63, wv = t >> 6;
    const int e0 = bbase[b], e1 = bbase[b + 1];
    const int n0 = b << BSH;
    const int nn = min(BS, N - n0);

    for (int i = t; i < BS; i += 256) h[i] = 0;
    __syncthreads();
    for (int i = e0 + t; i < e1; i += 256) atomicAdd(&h[rec[3 * i + 1] - n0], 1);
    __syncthreads();
    // exclusive scan of h[0..BS) with 4 per thread; write off[]
    {
        int j0 = 4 * t;
        int l0 = h[j0], l1 = h[j0 + 1], l2 = h[j0 + 2], l3 = h[j0 + 3];
        int s = l0 + l1 + l2 + l3;
        int inc = s;
        #pragma unroll
        for (int d = 1; d < 64; d <<= 1) { int u = __shfl_up(inc, d); if (lane >= d) inc += u; }
        if (lane == 63) wt[wv] = inc;
        __syncthreads();
        int base = 0;
        for (int w2 = 0; w2 < wv; ++w2) base += wt[w2];
        int ex = base + inc - s;
        int e_[4] = {ex, ex + l0, ex + l0 + l1, ex + l0 + l1 + l2};
        __syncthreads();          // everyone done reading h before overwrite
        #pragma unroll
        for (int k = 0; k < 4; ++k) {
            h[j0 + k] = e_[k];
            if (j0 + k < nn) off[n0 + j0 + k] = e0 + e_[k];
        }
    }
    __syncthreads();
    for (int i = e0 + t; i < e1; i += 256) {
        int d = rec[3 * i + 1] - n0;
        int pos = atomicAdd(&h[d], 1);
        ed[e0 + pos] = make_int2(rec[3 * i], rec[3 * i + 2]);
    }
}

// ---------------- f32 -> bf16 row pack ----------------
__global__ __launch_bounds__(256)
void pack_kernel(const float* __restrict__ in, unsigned short* __restrict__ outb, long n4) {
    long i = blockIdx.x * blockDim.x + threadIdx.x;
    long stride = (long)gridDim.x * blockDim.x;
    for (; i < n4; i += stride) {
        float4 v = ((const float4*)in)[i];
        ushort4 o;
        o.x = f2bf(v.x); o.y = f2bf(v.y); o.z = f2bf(v.z); o.w = f2bf(v.w);
        *(ushort4*)&outb[i * 4] = o;
    }
}

// ---------------- pull aggregation, bf16 rows ----------------
__device__ __forceinline__ void acc8(float* a, int4 r, float w) {
    #pragma unroll
    for (int j = 0; j < 4; ++j) {
        int bits = (&r.x)[j];
        float f0 = __int_as_float(bits << 16);
        float f1 = __int_as_float(bits & 0xffff0000);
        a[2 * j]     += f0 * w;
        a[2 * j + 1] += f1 * w;
    }
}

__global__ __launch_bounds__(256)
void gather_bf16in(const unsigned short* __restrict__ X,
                   const int* __restrict__ off, const int2* __restrict__ ed,
                   const float* __restrict__ Dn,
                   unsigned short* __restrict__ outb,
                   float* __restrict__ outf, long ocol0, int N) {
    const int tid = threadIdx.x;
    const int l = tid & 15;
    const int n = blockIdx.x * 16 + (tid >> 4);
    if (n >= N) return;
    const int beg = off[n], end = off[n + 1];
    float a[8] = {0.f, 0.f, 0.f, 0.f, 0.f, 0.f, 0.f, 0.f};
    const unsigned short* Xc = X + 8 * l;
    int i = beg;
    for (; i + 3 < end; i += 4) {
        int2 e0 = ed[i], e1 = ed[i + 1], e2 = ed[i + 2], e3 = ed[i + 3];
        int4 r0 = *(const int4*)(Xc + (long)e0.x * 128);
        int4 r1 = *(const int4*)(Xc + (long)e1.x * 128);
        int4 r2 = *(const int4*)(Xc + (long)e2.x * 128);
        int4 r3 = *(const int4*)(Xc + (long)e3.x * 128);
        acc8(a, r0, __int_as_float(e0.y));
        acc8(a, r1, __int_as_float(e1.y));
        acc8(a, r2, __int_as_float(e2.y));
        acc8(a, r3, __int_as_float(e3.y));
    }
    for (; i < end; ++i) {
        int2 e0 = ed[i];
        int4 r0 = *(const int4*)(Xc + (long)e0.x * 128);
        acc8(a, r0, __int_as_float(e0.y));
    }
    const float dn = Dn[n];
    #pragma unroll
    for (int j = 0; j < 8; ++j) a[j] *= dn;
    if (outb) {
        int4 o;
        #pragma unroll
        for (int j = 0; j < 4; ++j) {
            unsigned lo = f2bf(a[2 * j]);
            unsigned hi = f2bf(a[2 * j + 1]);
            (&o.x)[j] = (int)((hi << 16) | lo);
        }
        *(int4*)&outb[(long)n * 128 + 8 * l] = o;
    } else {
        float* p = outf + (long)n * OUT_STRIDE + ocol0 + 8 * l;
        *(float4*)p       = make_float4(a[0], a[1], a[2], a[3]);
        *(float4*)(p + 4) = make_float4(a[4], a[5], a[6], a[7]);
    }
}

// ---------------- legacy push scatter (fallback) ----------------
__global__ __launch_bounds__(256)
void scatter_kernel(const float* X, long xstride, long xcol0,
                    const int* __restrict__ src, const int* __restrict__ dst,
                    const float* __restrict__ w, const float* __restrict__ Dn,
                    int useDn, float* out, long ocol0, int nE)
{
    const int lane = threadIdx.x & 63;
    const int wave = (int)((blockIdx.x * blockDim.x + threadIdx.x) >> 6);
    const int nWaves = (int)((gridDim.x * blockDim.x) >> 6);
    for (int e = wave; e < nE; e += nWaves) {
        const int s = src[e];
        const int d = dst[e];
        float ww = w[e];
        if (useDn) ww *= Dn[s];
        const float2 v = *(const float2*)(X + (long)s * xstride + xcol0 + 2 * lane);
        float* o = out + (long)d * OUT_STRIDE + ocol0 + 2 * lane;
        atomicAdd(o, v.x * ww);
        atomicAdd(o + 1, v.y * ww);
    }
}

// ---------------- fused GEMM (bf16 MFMA) + bias + ReLU + LayerNorm ----------------
__global__ __launch_bounds__(256)
void transform_kernel(const void* x0, int f0, long s0,
                      const void* x1, int f1, long s1,
                      const void* x2, int f2, long s2,
                      const float* __restrict__ Dn,
                      const float* __restrict__ Wf,
                      const float* __restrict__ bf,
                      const float* __restrict__ scf,
                      const float* __restrict__ off,
                      float* out, int N, int applyDn)
{
    const int hop = blockIdx.y;
    const int tid = threadIdx.x;
    const int lane = tid & 63;
    const int wv = tid >> 6;

    constexpr int XS = 136;
    __shared__ __attribute__((aligned(16))) short Wl[128 * XS];
    __shared__ __attribute__((aligned(16))) short Xl[64 * XS];

    const float4* W4 = (const float4*)(Wf + (long)hop * 128 * 128);
    for (int idx = tid; idx < 128 * 32; idx += 256) {
        float4 v = W4[idx];
        int row = idx >> 5;
        int col = (idx & 31) * 4;
        short* p = &Wl[row * XS + col];
        p[0] = f2bf(v.x); p[1] = f2bf(v.y); p[2] = f2bf(v.z); p[3] = f2bf(v.w);
    }
    const void* xp = (hop == 0) ? x0 : (hop == 1) ? x1 : x2;
    const int fmt  = (hop == 0) ? f0 : (hop == 1) ? f1 : f2;
    const long xs  = (hop == 0) ? s0 : (hop == 1) ? s1 : s2;
    const int n0 = blockIdx.x * 64;
    if (fmt) {
        const unsigned short* xb = (const unsigned short*)xp;
        for (int idx = tid; idx < 64 * 16; idx += 256) {
            int r = idx >> 4;
            int c = (idx & 15) * 8;
            int n = n0 + r;
            int4 v = make_int4(0, 0, 0, 0);
            if (n < N) v = *(const int4*)(xb + (long)n * xs + c);
            *(int4*)&Xl[r * XS + c] = v;
        }
    } else {
        const float* xf = (const float*)xp;
        for (int idx = tid; idx < 64 * 32; idx += 256) {
            int r = idx >> 5;
            int col = (idx & 31) * 4;
            int n = n0 + r;
            float4 v = make_float4(0.f, 0.f, 0.f, 0.f);
            float m = 1.0f;
            if (n < N) {
                v = *(const float4*)(xf + (long)n * xs + col);
                if (applyDn && hop > 0) m = Dn[n];
            }
            short* p = &Xl[r * XS + col];
            p[0] = f2bf(v.x * m); p[1] = f2bf(v.y * m); p[2] = f2bf(v.z * m); p[3] = f2bf(v.w * m);
        }
    }
    __syncthreads();

    f32x4 acc[8];
    #pragma unroll
    for (int c = 0; c < 8; ++c) acc[c] = (f32x4){0.f, 0.f, 0.f, 0.f};
    const int rsub = lane & 15;
    const int g = lane >> 4;
    const short* xbase = &Xl[(wv * 16 + rsub) * XS + g * 8];
    const short* wbase = &Wl[rsub * XS + g * 8];
    #pragma unroll
    for (int kk = 0; kk < 4; ++kk) {
        bf16x8 a = *(const bf16x8*)(xbase + kk * 32);
        #pragma unroll
        for (int c = 0; c < 8; ++c) {
            bf16x8 bb = *(const bf16x8*)(wbase + c * 16 * XS + kk * 32);
            acc[c] = __builtin_amdgcn_mfma_f32_16x16x32_bf16(a, bb, acc[c], 0, 0, 0);
        }
    }

    const float* bp = bf  + hop * 128;
    const float* sp = scf + hop * 128;
    const float* op = off + hop * 128;
    float sum[4] = {0.f, 0.f, 0.f, 0.f};
    float ssq[4] = {0.f, 0.f, 0.f, 0.f};
    #pragma unroll
    for (int c = 0; c < 8; ++c) {
        float bias = bp[c * 16 + rsub];
        #pragma unroll
        for (int r = 0; r < 4; ++r) {
            float h = acc[c][r] + bias;
            h = fmaxf(h, 0.0f);
            acc[c][r] = h;
            sum[r] += h;
            ssq[r] += h * h;
        }
    }
    #pragma unroll
    for (int msk = 1; msk < 16; msk <<= 1) {
        #pragma unroll
        for (int r = 0; r < 4; ++r) {
            sum[r] += __shfl_xor(sum[r], msk);
            ssq[r] += __shfl_xor(ssq[r], msk);
        }
    }
    #pragma unroll
    for (int r = 0; r < 4; ++r) {
        int n = n0 + wv * 16 + g * 4 + r;
        if (n >= N) continue;
        float mean = sum[r] * (1.0f / 128.0f);
        float var = ssq[r] * (1.0f / 128.0f) - mean * mean + EPSV;
        float inv = rsqrtf(var);
        float* orow = out + (long)n * OUT_STRIDE + hop * 128;
        #pragma unroll
        for (int c = 0; c < 8; ++c) {
            int col = c * 16 + rsub;
            orow[col] = (acc[c][r] - mean) * sp[col] * inv + op[col];
        }
    }
}

extern "C" void kernel_launch(void* const* d_in, const int* in_sizes, int n_in,
                              void* d_out, int out_size, void* d_ws, size_t ws_size,
                              hipStream_t stream) {
    const float* features = (const float*)d_in[0];
    const int*   src      = (const int*)d_in[1];
    const int*   dst      = (const int*)d_in[2];
    const float* w        = (const float*)d_in[3];
    const float* Dn       = (const float*)d_in[4];
    const float* W        = (const float*)d_in[5];
    const float* b        = (const float*)d_in[6];
    const float* scale    = (const float*)d_in[7];
    const float* offset   = (const float*)d_in[8];
    float* out = (float*)d_out;
    const int N = in_sizes[0] / 128;
    const int E = in_sizes[1];
    const int NB = (N + BS - 1) >> BSH;

    // ws layout (ints): off[N+1] | ed[2E] | bcnt[NB] bbase[NB+1] bcur[NB] | union{rec[3E] ; featb[64N] h1b[64N] (h2b[64N])}
    const size_t o_off = 0;
    const size_t o_ed  = ((size_t)N + 1 + 3) & ~(size_t)3;
    const size_t o_b   = o_ed + 2 * (size_t)E;
    const size_t o_uni = (o_b + 3 * (size_t)NB + 1 + 3) & ~(size_t)3;
    const size_t uni2  = (size_t)128 * N > 3 * (size_t)E ? (size_t)128 * N : 3 * (size_t)E;
    const size_t uni3  = (size_t)192 * N > 3 * (size_t)E ? (size_t)192 * N : 3 * (size_t)E;
    const size_t need2 = (o_uni + uni2) * 4;
    const size_t need3 = (o_uni + uni3) * 4;
    dim3 tg((N + 63) / 64, 3);

    if (NB <= NBMAX && ws_size >= need2) {
        int* ws_i  = (int*)d_ws;
        int* off   = ws_i + o_off;
        int2* ed   = (int2*)(ws_i + o_ed);
        int* bcnt  = ws_i + o_b;
        int* bbase = bcnt + NB;
        int* bcur  = bbase + NB + 1;
        int* rec   = ws_i + o_uni;
        unsigned short* featb = (unsigned short*)(ws_i + o_uni);
        unsigned short* h1b   = featb + (size_t)N * 128;
        unsigned short* h2b   = h1b + (size_t)N * 128;
        const int use_h2b = (ws_size >= need3);

        hipMemsetAsync(bcnt, 0, (size_t)NB * 4, stream);
        bhist_kernel<<<512, 256, 0, stream>>>(dst, bcnt, E, NB);
        bscan_kernel<<<1, 256, 0, stream>>>(bcnt, bbase, bcur, off, NB, N, E);
        multisplit_kernel<<<(E + CH - 1) / CH, 256, 0, stream>>>(src, dst, w, bcur, rec, E);
        bucket_csr_kernel<<<NB, 256, 0, stream>>>(rec, bbase, off, ed, N);

        // rec is dead now; featb/h1b reuse its space
        pack_kernel<<<2048, 256, 0, stream>>>(features, featb, (long)N * 32);
        gather_bf16in<<<(N + 15) / 16, 256, 0, stream>>>(featb, off, ed, Dn, h1b, nullptr, 0, N);
        if (use_h2b) {
            gather_bf16in<<<(N + 15) / 16, 256, 0, stream>>>(h1b, off, ed, Dn, h2b, nullptr, 0, N);
            transform_kernel<<<tg, 256, 0, stream>>>(
                featb, 1, 128, h1b, 1, 128, h2b, 1, 128,
                Dn, W, b, scale, offset, out, N, 0);
        } else {
            gather_bf16in<<<(N + 15) / 16, 256, 0, stream>>>(h1b, off, ed, Dn, nullptr, out, 256, N);
            transform_kernel<<<tg, 256, 0, stream>>>(
                featb, 1, 128, h1b, 1, 128, out + 256, 0, OUT_STRIDE,
                Dn, W, b, scale, offset, out, N, 0);
        }
    } else {
        // fallback: atomic scatter path (raw agg stored; Dn applied on read)
        hipMemsetAsync(out, 0, (size_t)out_size * sizeof(float), stream);
        scatter_kernel<<<2048, 256, 0, stream>>>(features, 128, 0, src, dst, w, Dn, 0, out, 128, E);
        scatter_kernel<<<2048, 256, 0, stream>>>(out, OUT_STRIDE, 128, src, dst, w, Dn, 1, out, 256, E);
        transform_kernel<<<tg, 256, 0, stream>>>(
            features, 0, 128, out + 128, 0, OUT_STRIDE, out + 256, 0, OUT_STRIDE,
            Dn, W, b, scale, offset, out, N, 1);
    }
}